// Round 4
// baseline (230.212 us; speedup 1.0000x reference)
//
#include <hip/hip_runtime.h>

#define N_NODES 32768
#define N_EDGES 16384
#define DEG 4
#define KPE 8
#define DIM 128
#define EDIM 64

typedef float f32x4 __attribute__((ext_vector_type(4)));
typedef __bf16 bf16x8 __attribute__((ext_vector_type(8)));
typedef __bf16 bf16x2 __attribute__((ext_vector_type(2)));
typedef unsigned short u16x8 __attribute__((ext_vector_type(8)));
typedef unsigned int u32;

static __device__ __forceinline__ unsigned short f2bf(float f) {
  union { float f; unsigned int u; } v; v.f = f;
  unsigned int r = (v.u + 0x7FFFu + ((v.u >> 16) & 1u)) >> 16;
  return (unsigned short)r;
}
static __device__ __forceinline__ float bflo(unsigned int v) {
  union { unsigned int u; float f; } x; x.u = v << 16; return x.f;
}
static __device__ __forceinline__ float bfhi(unsigned int v) {
  union { unsigned int u; float f; } x; x.u = v & 0xffff0000u; return x.f;
}

#if __has_builtin(__builtin_amdgcn_fdot2_f32_bf16)
static __device__ __forceinline__ float dot2bf(unsigned int a, unsigned int b, float c) {
  return __builtin_amdgcn_fdot2_f32_bf16(
      __builtin_bit_cast(bf16x2, a), __builtin_bit_cast(bf16x2, b), c, false);
}
#else
static __device__ __forceinline__ float dot2bf(unsigned int a, unsigned int b, float c) {
  c = fmaf(bflo(a), bflo(b), c);
  return fmaf(bfhi(a), bfhi(b), c);
}
#endif

// ---------------- weight combine: CW=[0.25*Wq@Wlin; Wk@Wlin; Wv@Wlin] (384x128),
// CWE = Wk@Wedge (128x64), Wob = bf16(Wo) ----------------
__global__ __launch_bounds__(256) void wprep_kernel(
    const float* __restrict__ Wq, const float* __restrict__ Wk,
    const float* __restrict__ Wv, const float* __restrict__ Wlin,
    const float* __restrict__ Wedge, const float* __restrict__ Wo,
    unsigned short* __restrict__ CW, unsigned short* __restrict__ CWE,
    unsigned short* __restrict__ Wob)
{
  int id = blockIdx.x * 256 + threadIdx.x;
  if (id < 384 * 128) {
    int j = id >> 7, i = id & 127;
    const float* wrow; float scale = 1.0f;
    if (j < 128)      { wrow = Wq + j * 128; scale = 0.25f; }
    else if (j < 256) { wrow = Wk + (j - 128) * 128; }
    else              { wrow = Wv + (j - 256) * 128; }
    float s = 0.f;
    #pragma unroll 8
    for (int m = 0; m < 128; ++m) s += wrow[m] * Wlin[m * 128 + i];
    CW[id] = f2bf(s * scale);
  } else if (id < 384 * 128 + 128 * 64) {
    int id2 = id - 384 * 128; int j = id2 >> 6, t = id2 & 63;
    float s = 0.f;
    #pragma unroll 8
    for (int m = 0; m < 128; ++m) s += Wk[j * 128 + m] * Wedge[m * 64 + t];
    CWE[id2] = f2bf(s);
  } else if (id < 384 * 128 + 128 * 64 + 128 * 128) {
    int id3 = id - (384 * 128 + 128 * 64);
    Wob[id3] = f2bf(Wo[id3]);
  }
}

// ---------------- G12: fused g1 + g2 (independent work, one launch) -----------
// blocks 0..511:  x[N,128] @ CW[384,128]^T -> qb / Kb / Vb (bf16)
// blocks 512..1023: edge_attr[E,64] @ CWE[128,64]^T + bk -> WeKb (bf16)
__global__ __launch_bounds__(256) void g12_kernel(
    const float* __restrict__ x, const unsigned short* __restrict__ CW,
    const float* __restrict__ bq, const float* __restrict__ bv,
    unsigned short* __restrict__ qb, unsigned short* __restrict__ Kb,
    unsigned short* __restrict__ Vb,
    const float* __restrict__ ea, const unsigned short* __restrict__ CWE,
    const float* __restrict__ bk, unsigned short* __restrict__ WeKb)
{
  const int wave = threadIdx.x >> 6, lane = threadIdx.x & 63;
  const int r16 = lane & 15, quad = lane >> 4;

  if (blockIdx.x < 512) {
    const int m0 = blockIdx.x * 64 + wave * 16;
    u16x8 av[4];
    const float* arow = x + (size_t)(m0 + r16) * DIM + quad * 8;
    #pragma unroll
    for (int kk = 0; kk < 4; ++kk) {
      float4 a0 = *(const float4*)(arow + kk * 32);
      float4 a1 = *(const float4*)(arow + kk * 32 + 4);
      u16x8 au;
      au[0] = f2bf(a0.x); au[1] = f2bf(a0.y); au[2] = f2bf(a0.z); au[3] = f2bf(a0.w);
      au[4] = f2bf(a1.x); au[5] = f2bf(a1.y); au[6] = f2bf(a1.z); au[7] = f2bf(a1.w);
      av[kk] = au;
    }
    #pragma unroll
    for (int g = 0; g < 6; ++g) {
      f32x4 acc[4];
      const f32x4 z = {0.f, 0.f, 0.f, 0.f};
      acc[0] = z; acc[1] = z; acc[2] = z; acc[3] = z;
      #pragma unroll
      for (int kk = 0; kk < 4; ++kk) {
        #pragma unroll
        for (int s = 0; s < 4; ++s) {
          u16x8 bu = *(const u16x8*)(CW + (size_t)(g * 64 + s * 16 + r16) * DIM + kk * 32 + quad * 8);
          acc[s] = __builtin_amdgcn_mfma_f32_16x16x32_bf16(
              __builtin_bit_cast(bf16x8, av[kk]), __builtin_bit_cast(bf16x8, bu), acc[s], 0, 0, 0);
        }
      }
      const int arr = g >> 1;               // 0:q 1:K 2:V
      const int colbase = (g & 1) * 64;
      unsigned short* dst = arr == 0 ? qb : (arr == 1 ? Kb : Vb);
      #pragma unroll
      for (int s = 0; s < 4; ++s) {
        int j = colbase + s * 16 + r16;
        float bias = arr == 0 ? 0.25f * bq[j] : (arr == 2 ? bv[j] : 0.f);
        #pragma unroll
        for (int r = 0; r < 4; ++r) {
          int m = m0 + quad * 4 + r;
          dst[(size_t)m * DIM + j] = f2bf(acc[s][r] + bias);
        }
      }
    }
  } else {
    const int idx = blockIdx.x - 512;
    const int m0 = (idx >> 1) * 64 + wave * 16;
    const int n0 = (idx & 1) * 64;
    f32x4 acc[4];
    const f32x4 z = {0.f, 0.f, 0.f, 0.f};
    acc[0] = z; acc[1] = z; acc[2] = z; acc[3] = z;
    const float* arow = ea + (size_t)(m0 + r16) * EDIM + quad * 8;
    #pragma unroll
    for (int kk = 0; kk < 2; ++kk) {
      float4 a0 = *(const float4*)(arow + kk * 32);
      float4 a1 = *(const float4*)(arow + kk * 32 + 4);
      u16x8 au;
      au[0] = f2bf(a0.x); au[1] = f2bf(a0.y); au[2] = f2bf(a0.z); au[3] = f2bf(a0.w);
      au[4] = f2bf(a1.x); au[5] = f2bf(a1.y); au[6] = f2bf(a1.z); au[7] = f2bf(a1.w);
      bf16x8 av = __builtin_bit_cast(bf16x8, au);
      #pragma unroll
      for (int s = 0; s < 4; ++s) {
        u16x8 bu = *(const u16x8*)(CWE + (size_t)(n0 + s * 16 + r16) * EDIM + kk * 32 + quad * 8);
        acc[s] = __builtin_amdgcn_mfma_f32_16x16x32_bf16(
            av, __builtin_bit_cast(bf16x8, bu), acc[s], 0, 0, 0);
      }
    }
    #pragma unroll
    for (int s = 0; s < 4; ++s) {
      int j = n0 + s * 16 + r16;
      float bias = bk[j];
      #pragma unroll
      for (int r = 0; r < 4; ++r) {
        int m = m0 + quad * 4 + r;
        WeKb[(size_t)m * DIM + j] = f2bf(acc[s][r] + bias);
      }
    }
  }
}

// ---------------- G3: per-node attention (1 block = 1 wave = 1 node) ----------
// ZERO divergent VMEM: all gathered rows (K:32, WeK:4, V:32) are wave-uniform
// row addresses -> global_load_lds DMA (1 instr = one 256B row = 2 cache lines,
// no dest VGPRs, cannot be sunk by the scheduler). LDS rows padded to 272 B so
// score-phase ds_read_b128 spreads uniformly over the 32 banks (256 stride
// would put all 64 lanes' 16B spans on the same 4 banks).
__global__ __launch_bounds__(64, 2) void attn_kernel(
    const unsigned short* __restrict__ qb, const unsigned short* __restrict__ Kb,
    const unsigned short* __restrict__ Vb, const unsigned short* __restrict__ WeKb,
    const int* __restrict__ nedges, const int* __restrict__ enodes,
    unsigned short* __restrict__ ctxb)
{
  __shared__ __align__(16) unsigned char ldsK[32 * 272];  // K rows, stride 272
  __shared__ __align__(16) unsigned char ldsV[32 * 272];  // V rows, stride 272
  __shared__ __align__(16) unsigned char ldsE[4 * 272];   // WeK rows
  __shared__ __align__(16) float ldsP[8][36];             // P, padded stride
  const int lane = threadIdx.x;
  const int n = blockIdx.x;
  const int l = lane & 31, half = lane >> 5;
  const int h = lane >> 3;                                 // ctx head

  // --- indices (all wave-uniform -> scalar loads) ---
  int4 e4 = *(const int4*)(nedges + (size_t)n * DEG);
  int4 m0 = *(const int4*)(enodes + (size_t)e4.x * KPE);
  int4 m1 = *(const int4*)(enodes + (size_t)e4.x * KPE + 4);
  int4 m2 = *(const int4*)(enodes + (size_t)e4.y * KPE);
  int4 m3 = *(const int4*)(enodes + (size_t)e4.y * KPE + 4);
  int4 m4 = *(const int4*)(enodes + (size_t)e4.z * KPE);
  int4 m5 = *(const int4*)(enodes + (size_t)e4.z * KPE + 4);
  int4 m6 = *(const int4*)(enodes + (size_t)e4.w * KPE);
  int4 m7 = *(const int4*)(enodes + (size_t)e4.w * KPE + 4);

  // --- q into regs (wave-uniform row, broadcast-friendly) ---
  const uint4* qp = (const uint4*)(qb + (size_t)n * DIM + half * 64);
  uint4 qv[8];
  #pragma unroll
  for (int ch = 0; ch < 8; ++ch) qv[ch] = qp[ch];

  // --- DMA staging: K rows, E rows, V rows (issue order = use order) ---
#define STAGE(ldsdst, table, row) do {                                          \
    const u32* gp_ = (const u32*)((table) + (size_t)(row) * DIM) + lane;        \
    __builtin_amdgcn_global_load_lds(                                           \
        (const __attribute__((address_space(1))) u32*)gp_,                      \
        (__attribute__((address_space(3))) u32*)(ldsdst), 4, 0, 0);             \
  } while (0)
  STAGE(ldsK + 0  * 272, Kb, m0.x); STAGE(ldsK + 1  * 272, Kb, m0.y);
  STAGE(ldsK + 2  * 272, Kb, m0.z); STAGE(ldsK + 3  * 272, Kb, m0.w);
  STAGE(ldsK + 4  * 272, Kb, m1.x); STAGE(ldsK + 5  * 272, Kb, m1.y);
  STAGE(ldsK + 6  * 272, Kb, m1.z); STAGE(ldsK + 7  * 272, Kb, m1.w);
  STAGE(ldsK + 8  * 272, Kb, m2.x); STAGE(ldsK + 9  * 272, Kb, m2.y);
  STAGE(ldsK + 10 * 272, Kb, m2.z); STAGE(ldsK + 11 * 272, Kb, m2.w);
  STAGE(ldsK + 12 * 272, Kb, m3.x); STAGE(ldsK + 13 * 272, Kb, m3.y);
  STAGE(ldsK + 14 * 272, Kb, m3.z); STAGE(ldsK + 15 * 272, Kb, m3.w);
  STAGE(ldsK + 16 * 272, Kb, m4.x); STAGE(ldsK + 17 * 272, Kb, m4.y);
  STAGE(ldsK + 18 * 272, Kb, m4.z); STAGE(ldsK + 19 * 272, Kb, m4.w);
  STAGE(ldsK + 20 * 272, Kb, m5.x); STAGE(ldsK + 21 * 272, Kb, m5.y);
  STAGE(ldsK + 22 * 272, Kb, m5.z); STAGE(ldsK + 23 * 272, Kb, m5.w);
  STAGE(ldsK + 24 * 272, Kb, m6.x); STAGE(ldsK + 25 * 272, Kb, m6.y);
  STAGE(ldsK + 26 * 272, Kb, m6.z); STAGE(ldsK + 27 * 272, Kb, m6.w);
  STAGE(ldsK + 28 * 272, Kb, m7.x); STAGE(ldsK + 29 * 272, Kb, m7.y);
  STAGE(ldsK + 30 * 272, Kb, m7.z); STAGE(ldsK + 31 * 272, Kb, m7.w);
  STAGE(ldsE + 0 * 272, WeKb, e4.x); STAGE(ldsE + 1 * 272, WeKb, e4.y);
  STAGE(ldsE + 2 * 272, WeKb, e4.z); STAGE(ldsE + 3 * 272, WeKb, e4.w);
  STAGE(ldsV + 0  * 272, Vb, m0.x); STAGE(ldsV + 1  * 272, Vb, m0.y);
  STAGE(ldsV + 2  * 272, Vb, m0.z); STAGE(ldsV + 3  * 272, Vb, m0.w);
  STAGE(ldsV + 4  * 272, Vb, m1.x); STAGE(ldsV + 5  * 272, Vb, m1.y);
  STAGE(ldsV + 6  * 272, Vb, m1.z); STAGE(ldsV + 7  * 272, Vb, m1.w);
  STAGE(ldsV + 8  * 272, Vb, m2.x); STAGE(ldsV + 9  * 272, Vb, m2.y);
  STAGE(ldsV + 10 * 272, Vb, m2.z); STAGE(ldsV + 11 * 272, Vb, m2.w);
  STAGE(ldsV + 12 * 272, Vb, m3.x); STAGE(ldsV + 13 * 272, Vb, m3.y);
  STAGE(ldsV + 14 * 272, Vb, m3.z); STAGE(ldsV + 15 * 272, Vb, m3.w);
  STAGE(ldsV + 16 * 272, Vb, m4.x); STAGE(ldsV + 17 * 272, Vb, m4.y);
  STAGE(ldsV + 18 * 272, Vb, m4.z); STAGE(ldsV + 19 * 272, Vb, m4.w);
  STAGE(ldsV + 20 * 272, Vb, m5.x); STAGE(ldsV + 21 * 272, Vb, m5.y);
  STAGE(ldsV + 22 * 272, Vb, m5.z); STAGE(ldsV + 23 * 272, Vb, m5.w);
  STAGE(ldsV + 24 * 272, Vb, m6.x); STAGE(ldsV + 25 * 272, Vb, m6.y);
  STAGE(ldsV + 26 * 272, Vb, m6.z); STAGE(ldsV + 27 * 272, Vb, m6.w);
  STAGE(ldsV + 28 * 272, Vb, m7.x); STAGE(ldsV + 29 * 272, Vb, m7.y);
  STAGE(ldsV + 30 * 272, Vb, m7.z); STAGE(ldsV + 31 * 272, Vb, m7.w);
#undef STAGE

  __syncthreads();   // vmcnt(0): all rows staged

  // --- scores: s[hi] = q . (K[l] + WeK[e(l)]) over this half's 64 dims ---
  const unsigned char* krow = ldsK + l * 272 + half * 128;
  const unsigned char* erow = ldsE + (l >> 3) * 272 + half * 128;
  float s[4] = {0.f, 0.f, 0.f, 0.f};
  #pragma unroll
  for (int ch = 0; ch < 8; ++ch) {
    uint4 kc = *(const uint4*)(krow + ch * 16);
    uint4 ec = *(const uint4*)(erow + ch * 16);
    const int hi = ch >> 1;
    float t = s[hi];
    t = dot2bf(qv[ch].x, kc.x, t); t = dot2bf(qv[ch].x, ec.x, t);
    t = dot2bf(qv[ch].y, kc.y, t); t = dot2bf(qv[ch].y, ec.y, t);
    t = dot2bf(qv[ch].z, kc.z, t); t = dot2bf(qv[ch].z, ec.z, t);
    t = dot2bf(qv[ch].w, kc.w, t); t = dot2bf(qv[ch].w, ec.w, t);
    s[hi] = t;
  }

  // --- softmax over the 32 keys (within each 32-lane half-group) ---
  #pragma unroll
  for (int hi = 0; hi < 4; ++hi) {
    float vmax = s[hi];
    #pragma unroll
    for (int off = 16; off >= 1; off >>= 1)
      vmax = fmaxf(vmax, __shfl_xor(vmax, off, 32));
    float ex = __expf(s[hi] - vmax);
    float sum = ex;
    #pragma unroll
    for (int off = 16; off >= 1; off >>= 1)
      sum += __shfl_xor(sum, off, 32);
    ldsP[half * 4 + hi][l] = ex / sum;
  }
  __syncthreads();   // P visible

  // --- ctx: lane = dim pair; V rows from LDS (uniform bank spread) ---
  float a0 = 0.f, a1 = 0.f;
  #pragma unroll
  for (int t = 0; t < 8; ++t) {
    float4 p4 = *(const float4*)&ldsP[h][t * 4];
    u32 v0 = *(const u32*)(ldsV + (t * 4 + 0) * 272 + lane * 4);
    u32 v1 = *(const u32*)(ldsV + (t * 4 + 1) * 272 + lane * 4);
    u32 v2 = *(const u32*)(ldsV + (t * 4 + 2) * 272 + lane * 4);
    u32 v3 = *(const u32*)(ldsV + (t * 4 + 3) * 272 + lane * 4);
    a0 = fmaf(p4.x, bflo(v0), a0); a1 = fmaf(p4.x, bfhi(v0), a1);
    a0 = fmaf(p4.y, bflo(v1), a0); a1 = fmaf(p4.y, bfhi(v1), a1);
    a0 = fmaf(p4.z, bflo(v2), a0); a1 = fmaf(p4.z, bfhi(v2), a1);
    a0 = fmaf(p4.w, bflo(v3), a0); a1 = fmaf(p4.w, bfhi(v3), a1);
  }
  unsigned int pk = (unsigned int)f2bf(a0) | ((unsigned int)f2bf(a1) << 16);
  *(unsigned int*)(ctxb + (size_t)n * DIM + lane * 2) = pk;
}

// ---------------- G4: ctx[N,128] @ Wo[128,128]^T + bo, ReLU -> out fp32 -------
__global__ __launch_bounds__(256) void g4_kernel(
    const unsigned short* __restrict__ ctxb, const unsigned short* __restrict__ Wob,
    const float* __restrict__ bo, float* __restrict__ out)
{
  const int wave = threadIdx.x >> 6, lane = threadIdx.x & 63;
  const int r16 = lane & 15, quad = lane >> 4;
  const int m0 = blockIdx.x * 64 + wave * 16;
  const int n0 = blockIdx.y * 64;

  f32x4 acc[4];
  const f32x4 z = {0.f, 0.f, 0.f, 0.f};
  acc[0] = z; acc[1] = z; acc[2] = z; acc[3] = z;

  #pragma unroll
  for (int kk = 0; kk < 4; ++kk) {
    u16x8 au = *(const u16x8*)(ctxb + (size_t)(m0 + r16) * DIM + kk * 32 + quad * 8);
    bf16x8 av = __builtin_bit_cast(bf16x8, au);
    #pragma unroll
    for (int s = 0; s < 4; ++s) {
      u16x8 bu = *(const u16x8*)(Wob + (size_t)(n0 + s * 16 + r16) * DIM + kk * 32 + quad * 8);
      acc[s] = __builtin_amdgcn_mfma_f32_16x16x32_bf16(
          av, __builtin_bit_cast(bf16x8, bu), acc[s], 0, 0, 0);
    }
  }

  #pragma unroll
  for (int s = 0; s < 4; ++s) {
    int j = n0 + s * 16 + r16;
    float bias = bo[j];
    #pragma unroll
    for (int r = 0; r < 4; ++r) {
      int m = m0 + quad * 4 + r;
      float v = acc[s][r] + bias;
      out[(size_t)m * DIM + j] = v > 0.f ? v : 0.f;
    }
  }
}

extern "C" void kernel_launch(void* const* d_in, const int* in_sizes, int n_in,
                              void* d_out, int out_size, void* d_ws, size_t ws_size,
                              hipStream_t stream)
{
  const float* x     = (const float*)d_in[0];
  const float* ea    = (const float*)d_in[1];
  const int* nedges  = (const int*)d_in[2];
  const int* enodes  = (const int*)d_in[3];
  const float* Wlin  = (const float*)d_in[4];
  const float* Wedge = (const float*)d_in[5];
  const float* Wq    = (const float*)d_in[6];
  const float* Wk    = (const float*)d_in[7];
  const float* Wv    = (const float*)d_in[8];
  const float* bq    = (const float*)d_in[9];
  const float* bk    = (const float*)d_in[10];
  const float* bv    = (const float*)d_in[11];
  const float* Wo    = (const float*)d_in[12];
  const float* bo    = (const float*)d_in[13];
  float* out = (float*)d_out;

  unsigned short* wsp = (unsigned short*)d_ws;
  unsigned short* CW   = wsp;  wsp += 384 * 128;
  unsigned short* CWE  = wsp;  wsp += 128 * 64;
  unsigned short* Wob  = wsp;  wsp += 128 * 128;
  unsigned short* qb   = wsp;  wsp += (size_t)N_NODES * DIM;
  unsigned short* Kb   = wsp;  wsp += (size_t)N_NODES * DIM;
  unsigned short* Vb   = wsp;  wsp += (size_t)N_NODES * DIM;
  unsigned short* WeKb = wsp;  wsp += (size_t)N_EDGES * DIM;
  unsigned short* ctxb = wsp;  wsp += (size_t)N_NODES * DIM;

  wprep_kernel<<<dim3(288), dim3(256), 0, stream>>>(Wq, Wk, Wv, Wlin, Wedge, Wo, CW, CWE, Wob);
  g12_kernel<<<dim3(1024), dim3(256), 0, stream>>>(x, CW, bq, bv, qb, Kb, Vb, ea, CWE, bk, WeKb);
  attn_kernel<<<dim3(32768), dim3(64), 0, stream>>>(qb, Kb, Vb, WeKb, nedges, enodes, ctxb);
  g4_kernel<<<dim3(512, 2), dim3(256), 0, stream>>>(ctxb, Wob, bo, out);
}

// Round 5
// 203.144 us; speedup vs baseline: 1.1332x; 1.1332x over previous
//
#include <hip/hip_runtime.h>

#define N_NODES 32768
#define N_EDGES 16384
#define DEG 4
#define KPE 8
#define DIM 128
#define EDIM 64

typedef float f32x4 __attribute__((ext_vector_type(4)));
typedef __bf16 bf16x8 __attribute__((ext_vector_type(8)));
typedef __bf16 bf16x2 __attribute__((ext_vector_type(2)));
typedef unsigned short u16x8 __attribute__((ext_vector_type(8)));
typedef unsigned int u32;

static __device__ __forceinline__ unsigned short f2bf(float f) {
  union { float f; unsigned int u; } v; v.f = f;
  unsigned int r = (v.u + 0x7FFFu + ((v.u >> 16) & 1u)) >> 16;
  return (unsigned short)r;
}
static __device__ __forceinline__ float bflo(unsigned int v) {
  union { unsigned int u; float f; } x; x.u = v << 16; return x.f;
}
static __device__ __forceinline__ float bfhi(unsigned int v) {
  union { unsigned int u; float f; } x; x.u = v & 0xffff0000u; return x.f;
}

#if __has_builtin(__builtin_amdgcn_fdot2_f32_bf16)
static __device__ __forceinline__ float dot2bf(unsigned int a, unsigned int b, float c) {
  return __builtin_amdgcn_fdot2_f32_bf16(
      __builtin_bit_cast(bf16x2, a), __builtin_bit_cast(bf16x2, b), c, false);
}
#else
static __device__ __forceinline__ float dot2bf(unsigned int a, unsigned int b, float c) {
  c = fmaf(bflo(a), bflo(b), c);
  return fmaf(bfhi(a), bfhi(b), c);
}
#endif

// ---------------- weight combine: CW=[0.25*Wq@Wlin; Wk@Wlin; Wv@Wlin] (384x128),
// CWE = Wk@Wedge (128x64), Wob = bf16(Wo) ----------------
__global__ __launch_bounds__(256) void wprep_kernel(
    const float* __restrict__ Wq, const float* __restrict__ Wk,
    const float* __restrict__ Wv, const float* __restrict__ Wlin,
    const float* __restrict__ Wedge, const float* __restrict__ Wo,
    unsigned short* __restrict__ CW, unsigned short* __restrict__ CWE,
    unsigned short* __restrict__ Wob)
{
  int id = blockIdx.x * 256 + threadIdx.x;
  if (id < 384 * 128) {
    int j = id >> 7, i = id & 127;
    const float* wrow; float scale = 1.0f;
    if (j < 128)      { wrow = Wq + j * 128; scale = 0.25f; }
    else if (j < 256) { wrow = Wk + (j - 128) * 128; }
    else              { wrow = Wv + (j - 256) * 128; }
    float s = 0.f;
    #pragma unroll 8
    for (int m = 0; m < 128; ++m) s += wrow[m] * Wlin[m * 128 + i];
    CW[id] = f2bf(s * scale);
  } else if (id < 384 * 128 + 128 * 64) {
    int id2 = id - 384 * 128; int j = id2 >> 6, t = id2 & 63;
    float s = 0.f;
    #pragma unroll 8
    for (int m = 0; m < 128; ++m) s += Wk[j * 128 + m] * Wedge[m * 64 + t];
    CWE[id2] = f2bf(s);
  } else if (id < 384 * 128 + 128 * 64 + 128 * 128) {
    int id3 = id - (384 * 128 + 128 * 64);
    Wob[id3] = f2bf(Wo[id3]);
  }
}

// ---------------- G12: fused g1 + g2 (independent work, one launch) -----------
__global__ __launch_bounds__(256) void g12_kernel(
    const float* __restrict__ x, const unsigned short* __restrict__ CW,
    const float* __restrict__ bq, const float* __restrict__ bv,
    unsigned short* __restrict__ qb, unsigned short* __restrict__ Kb,
    unsigned short* __restrict__ Vb,
    const float* __restrict__ ea, const unsigned short* __restrict__ CWE,
    const float* __restrict__ bk, unsigned short* __restrict__ WeKb)
{
  const int wave = threadIdx.x >> 6, lane = threadIdx.x & 63;
  const int r16 = lane & 15, quad = lane >> 4;

  if (blockIdx.x < 512) {
    const int m0 = blockIdx.x * 64 + wave * 16;
    u16x8 av[4];
    const float* arow = x + (size_t)(m0 + r16) * DIM + quad * 8;
    #pragma unroll
    for (int kk = 0; kk < 4; ++kk) {
      float4 a0 = *(const float4*)(arow + kk * 32);
      float4 a1 = *(const float4*)(arow + kk * 32 + 4);
      u16x8 au;
      au[0] = f2bf(a0.x); au[1] = f2bf(a0.y); au[2] = f2bf(a0.z); au[3] = f2bf(a0.w);
      au[4] = f2bf(a1.x); au[5] = f2bf(a1.y); au[6] = f2bf(a1.z); au[7] = f2bf(a1.w);
      av[kk] = au;
    }
    #pragma unroll
    for (int g = 0; g < 6; ++g) {
      f32x4 acc[4];
      const f32x4 z = {0.f, 0.f, 0.f, 0.f};
      acc[0] = z; acc[1] = z; acc[2] = z; acc[3] = z;
      #pragma unroll
      for (int kk = 0; kk < 4; ++kk) {
        #pragma unroll
        for (int s = 0; s < 4; ++s) {
          u16x8 bu = *(const u16x8*)(CW + (size_t)(g * 64 + s * 16 + r16) * DIM + kk * 32 + quad * 8);
          acc[s] = __builtin_amdgcn_mfma_f32_16x16x32_bf16(
              __builtin_bit_cast(bf16x8, av[kk]), __builtin_bit_cast(bf16x8, bu), acc[s], 0, 0, 0);
        }
      }
      const int arr = g >> 1;               // 0:q 1:K 2:V
      const int colbase = (g & 1) * 64;
      unsigned short* dst = arr == 0 ? qb : (arr == 1 ? Kb : Vb);
      #pragma unroll
      for (int s = 0; s < 4; ++s) {
        int j = colbase + s * 16 + r16;
        float bias = arr == 0 ? 0.25f * bq[j] : (arr == 2 ? bv[j] : 0.f);
        #pragma unroll
        for (int r = 0; r < 4; ++r) {
          int m = m0 + quad * 4 + r;
          dst[(size_t)m * DIM + j] = f2bf(acc[s][r] + bias);
        }
      }
    }
  } else {
    const int idx = blockIdx.x - 512;
    const int m0 = (idx >> 1) * 64 + wave * 16;
    const int n0 = (idx & 1) * 64;
    f32x4 acc[4];
    const f32x4 z = {0.f, 0.f, 0.f, 0.f};
    acc[0] = z; acc[1] = z; acc[2] = z; acc[3] = z;
    const float* arow = ea + (size_t)(m0 + r16) * EDIM + quad * 8;
    #pragma unroll
    for (int kk = 0; kk < 2; ++kk) {
      float4 a0 = *(const float4*)(arow + kk * 32);
      float4 a1 = *(const float4*)(arow + kk * 32 + 4);
      u16x8 au;
      au[0] = f2bf(a0.x); au[1] = f2bf(a0.y); au[2] = f2bf(a0.z); au[3] = f2bf(a0.w);
      au[4] = f2bf(a1.x); au[5] = f2bf(a1.y); au[6] = f2bf(a1.z); au[7] = f2bf(a1.w);
      bf16x8 av = __builtin_bit_cast(bf16x8, au);
      #pragma unroll
      for (int s = 0; s < 4; ++s) {
        u16x8 bu = *(const u16x8*)(CWE + (size_t)(n0 + s * 16 + r16) * EDIM + kk * 32 + quad * 8);
        acc[s] = __builtin_amdgcn_mfma_f32_16x16x32_bf16(
            av, __builtin_bit_cast(bf16x8, bu), acc[s], 0, 0, 0);
      }
    }
    #pragma unroll
    for (int s = 0; s < 4; ++s) {
      int j = n0 + s * 16 + r16;
      float bias = bk[j];
      #pragma unroll
      for (int r = 0; r < 4; ++r) {
        int m = m0 + quad * 4 + r;
        WeKb[(size_t)m * DIM + j] = f2bf(acc[s][r] + bias);
      }
    }
  }
}

// ---------------- G3: per-node attention (1 block = 1 wave = 1 node) ----------
// Hybrid staging tuned from r3/r4 evidence:
//   K rows (divergent-by-lane in score phase) -> LDS via global_load_lds DMA
//     (uniform-row, 1 instr = 256 B, zero dest VGPRs).  LDS only ~11 KB ->
//     ~14 blocks/CU (r4's 19.5 KB halved occupancy -- the regression cause).
//   V rows + q -> coalesced register loads (V[u]+lane*4 is a 256 B wave read).
//   NO __syncthreads: single-wave block; one asm s_waitcnt vmcnt(0) with
//   memory clobber pins all loads above it (defeats compiler sinking, the
//   r2/r3 failure) AND is the LDS-DMA completion fence.
__global__ __launch_bounds__(64, 4) void attn_kernel(
    const unsigned short* __restrict__ qb, const unsigned short* __restrict__ Kb,
    const unsigned short* __restrict__ Vb, const unsigned short* __restrict__ WeKb,
    const int* __restrict__ nedges, const int* __restrict__ enodes,
    unsigned short* __restrict__ ctxb)
{
  __shared__ __align__(16) unsigned char ldsK[32 * 272];  // K rows, stride 272
  __shared__ __align__(16) unsigned char ldsE[4 * 272];   // WeK rows
  __shared__ __align__(16) float ldsP[8][36];             // P, padded stride
  const int lane = threadIdx.x;
  const int n = blockIdx.x;
  const int l = lane & 31, half = lane >> 5;
  const int h = lane >> 3;                                 // ctx head
  const int c0 = lane * 2;                                 // ctx dim pair

  // --- indices (wave-uniform rows) ---
  int4 e4 = *(const int4*)(nedges + (size_t)n * DEG);
  int4 m0 = *(const int4*)(enodes + (size_t)e4.x * KPE);
  int4 m1 = *(const int4*)(enodes + (size_t)e4.x * KPE + 4);
  int4 m2 = *(const int4*)(enodes + (size_t)e4.y * KPE);
  int4 m3 = *(const int4*)(enodes + (size_t)e4.y * KPE + 4);
  int4 m4 = *(const int4*)(enodes + (size_t)e4.z * KPE);
  int4 m5 = *(const int4*)(enodes + (size_t)e4.z * KPE + 4);
  int4 m6 = *(const int4*)(enodes + (size_t)e4.w * KPE);
  int4 m7 = *(const int4*)(enodes + (size_t)e4.w * KPE + 4);

  // --- K + WeK rows -> LDS DMA (consumed first; issued first) ---
#define STAGE(ldsdst, table, row) do {                                          \
    const u32* gp_ = (const u32*)((table) + (size_t)(row) * DIM) + lane;        \
    __builtin_amdgcn_global_load_lds(                                           \
        (const __attribute__((address_space(1))) u32*)gp_,                      \
        (__attribute__((address_space(3))) u32*)(ldsdst), 4, 0, 0);             \
  } while (0)
  STAGE(ldsK + 0  * 272, Kb, m0.x); STAGE(ldsK + 1  * 272, Kb, m0.y);
  STAGE(ldsK + 2  * 272, Kb, m0.z); STAGE(ldsK + 3  * 272, Kb, m0.w);
  STAGE(ldsK + 4  * 272, Kb, m1.x); STAGE(ldsK + 5  * 272, Kb, m1.y);
  STAGE(ldsK + 6  * 272, Kb, m1.z); STAGE(ldsK + 7  * 272, Kb, m1.w);
  STAGE(ldsK + 8  * 272, Kb, m2.x); STAGE(ldsK + 9  * 272, Kb, m2.y);
  STAGE(ldsK + 10 * 272, Kb, m2.z); STAGE(ldsK + 11 * 272, Kb, m2.w);
  STAGE(ldsK + 12 * 272, Kb, m3.x); STAGE(ldsK + 13 * 272, Kb, m3.y);
  STAGE(ldsK + 14 * 272, Kb, m3.z); STAGE(ldsK + 15 * 272, Kb, m3.w);
  STAGE(ldsK + 16 * 272, Kb, m4.x); STAGE(ldsK + 17 * 272, Kb, m4.y);
  STAGE(ldsK + 18 * 272, Kb, m4.z); STAGE(ldsK + 19 * 272, Kb, m4.w);
  STAGE(ldsK + 20 * 272, Kb, m5.x); STAGE(ldsK + 21 * 272, Kb, m5.y);
  STAGE(ldsK + 22 * 272, Kb, m5.z); STAGE(ldsK + 23 * 272, Kb, m5.w);
  STAGE(ldsK + 24 * 272, Kb, m6.x); STAGE(ldsK + 25 * 272, Kb, m6.y);
  STAGE(ldsK + 26 * 272, Kb, m6.z); STAGE(ldsK + 27 * 272, Kb, m6.w);
  STAGE(ldsK + 28 * 272, Kb, m7.x); STAGE(ldsK + 29 * 272, Kb, m7.y);
  STAGE(ldsK + 30 * 272, Kb, m7.z); STAGE(ldsK + 31 * 272, Kb, m7.w);
  STAGE(ldsE + 0 * 272, WeKb, e4.x); STAGE(ldsE + 1 * 272, WeKb, e4.y);
  STAGE(ldsE + 2 * 272, WeKb, e4.z); STAGE(ldsE + 3 * 272, WeKb, e4.w);
#undef STAGE

  // --- q (wave-uniform row) + V rows (coalesced 256 B wave reads) -> regs ---
  const uint4* qp = (const uint4*)(qb + (size_t)n * DIM + half * 64);
  uint4 qv[8];
  #pragma unroll
  for (int ch = 0; ch < 8; ++ch) qv[ch] = qp[ch];

  u32 vv[32];
#define VLOAD(t, row) vv[t] = *(const u32*)(Vb + (size_t)(row) * DIM + c0)
  VLOAD(0,  m0.x); VLOAD(1,  m0.y); VLOAD(2,  m0.z); VLOAD(3,  m0.w);
  VLOAD(4,  m1.x); VLOAD(5,  m1.y); VLOAD(6,  m1.z); VLOAD(7,  m1.w);
  VLOAD(8,  m2.x); VLOAD(9,  m2.y); VLOAD(10, m2.z); VLOAD(11, m2.w);
  VLOAD(12, m3.x); VLOAD(13, m3.y); VLOAD(14, m3.z); VLOAD(15, m3.w);
  VLOAD(16, m4.x); VLOAD(17, m4.y); VLOAD(18, m4.z); VLOAD(19, m4.w);
  VLOAD(20, m5.x); VLOAD(21, m5.y); VLOAD(22, m5.z); VLOAD(23, m5.w);
  VLOAD(24, m6.x); VLOAD(25, m6.y); VLOAD(26, m6.z); VLOAD(27, m6.w);
  VLOAD(28, m7.x); VLOAD(29, m7.y); VLOAD(30, m7.z); VLOAD(31, m7.w);
#undef VLOAD

  // Pin every load above this point and drain the LDS-DMA queue.
  asm volatile("s_waitcnt vmcnt(0)" ::: "memory");

  // --- scores: s[hi] = q . (K[l] + WeK[e(l)]) over this half's 64 dims ---
  const unsigned char* krow = ldsK + l * 272 + half * 128;
  const unsigned char* erow = ldsE + (l >> 3) * 272 + half * 128;
  float s[4] = {0.f, 0.f, 0.f, 0.f};
  #pragma unroll
  for (int ch = 0; ch < 8; ++ch) {
    uint4 kc = *(const uint4*)(krow + ch * 16);
    uint4 ec = *(const uint4*)(erow + ch * 16);
    const int hi = ch >> 1;
    float t = s[hi];
    t = dot2bf(qv[ch].x, kc.x, t); t = dot2bf(qv[ch].x, ec.x, t);
    t = dot2bf(qv[ch].y, kc.y, t); t = dot2bf(qv[ch].y, ec.y, t);
    t = dot2bf(qv[ch].z, kc.z, t); t = dot2bf(qv[ch].z, ec.z, t);
    t = dot2bf(qv[ch].w, kc.w, t); t = dot2bf(qv[ch].w, ec.w, t);
    s[hi] = t;
  }

  // --- softmax over the 32 keys (within each 32-lane half-group) ---
  #pragma unroll
  for (int hi = 0; hi < 4; ++hi) {
    float vmax = s[hi];
    #pragma unroll
    for (int off = 16; off >= 1; off >>= 1)
      vmax = fmaxf(vmax, __shfl_xor(vmax, off, 32));
    float ex = __expf(s[hi] - vmax);
    float sum = ex;
    #pragma unroll
    for (int off = 16; off >= 1; off >>= 1)
      sum += __shfl_xor(sum, off, 32);
    ldsP[half * 4 + hi][l] = ex / sum;
  }
  // single-wave block: LDS write->read ordering is just lgkmcnt (compiler).

  // --- ctx: lane = dim pair; V in registers, P via LDS float4 broadcast ---
  float a0 = 0.f, a1 = 0.f;
  #pragma unroll
  for (int t = 0; t < 8; ++t) {
    float4 p4 = *(const float4*)&ldsP[h][t * 4];
    a0 = fmaf(p4.x, bflo(vv[t * 4 + 0]), a0); a1 = fmaf(p4.x, bfhi(vv[t * 4 + 0]), a1);
    a0 = fmaf(p4.y, bflo(vv[t * 4 + 1]), a0); a1 = fmaf(p4.y, bfhi(vv[t * 4 + 1]), a1);
    a0 = fmaf(p4.z, bflo(vv[t * 4 + 2]), a0); a1 = fmaf(p4.z, bfhi(vv[t * 4 + 2]), a1);
    a0 = fmaf(p4.w, bflo(vv[t * 4 + 3]), a0); a1 = fmaf(p4.w, bfhi(vv[t * 4 + 3]), a1);
  }
  unsigned int pk = (unsigned int)f2bf(a0) | ((unsigned int)f2bf(a1) << 16);
  *(unsigned int*)(ctxb + (size_t)n * DIM + c0) = pk;
}

// ---------------- G4: ctx[N,128] @ Wo[128,128]^T + bo, ReLU -> out fp32 -------
__global__ __launch_bounds__(256) void g4_kernel(
    const unsigned short* __restrict__ ctxb, const unsigned short* __restrict__ Wob,
    const float* __restrict__ bo, float* __restrict__ out)
{
  const int wave = threadIdx.x >> 6, lane = threadIdx.x & 63;
  const int r16 = lane & 15, quad = lane >> 4;
  const int m0 = blockIdx.x * 64 + wave * 16;
  const int n0 = blockIdx.y * 64;

  f32x4 acc[4];
  const f32x4 z = {0.f, 0.f, 0.f, 0.f};
  acc[0] = z; acc[1] = z; acc[2] = z; acc[3] = z;

  #pragma unroll
  for (int kk = 0; kk < 4; ++kk) {
    u16x8 au = *(const u16x8*)(ctxb + (size_t)(m0 + r16) * DIM + kk * 32 + quad * 8);
    bf16x8 av = __builtin_bit_cast(bf16x8, au);
    #pragma unroll
    for (int s = 0; s < 4; ++s) {
      u16x8 bu = *(const u16x8*)(Wob + (size_t)(n0 + s * 16 + r16) * DIM + kk * 32 + quad * 8);
      acc[s] = __builtin_amdgcn_mfma_f32_16x16x32_bf16(
          av, __builtin_bit_cast(bf16x8, bu), acc[s], 0, 0, 0);
    }
  }

  #pragma unroll
  for (int s = 0; s < 4; ++s) {
    int j = n0 + s * 16 + r16;
    float bias = bo[j];
    #pragma unroll
    for (int r = 0; r < 4; ++r) {
      int m = m0 + quad * 4 + r;
      float v = acc[s][r] + bias;
      out[(size_t)m * DIM + j] = v > 0.f ? v : 0.f;
    }
  }
}

extern "C" void kernel_launch(void* const* d_in, const int* in_sizes, int n_in,
                              void* d_out, int out_size, void* d_ws, size_t ws_size,
                              hipStream_t stream)
{
  const float* x     = (const float*)d_in[0];
  const float* ea    = (const float*)d_in[1];
  const int* nedges  = (const int*)d_in[2];
  const int* enodes  = (const int*)d_in[3];
  const float* Wlin  = (const float*)d_in[4];
  const float* Wedge = (const float*)d_in[5];
  const float* Wq    = (const float*)d_in[6];
  const float* Wk    = (const float*)d_in[7];
  const float* Wv    = (const float*)d_in[8];
  const float* bq    = (const float*)d_in[9];
  const float* bk    = (const float*)d_in[10];
  const float* bv    = (const float*)d_in[11];
  const float* Wo    = (const float*)d_in[12];
  const float* bo    = (const float*)d_in[13];
  float* out = (float*)d_out;

  unsigned short* wsp = (unsigned short*)d_ws;
  unsigned short* CW   = wsp;  wsp += 384 * 128;
  unsigned short* CWE  = wsp;  wsp += 128 * 64;
  unsigned short* Wob  = wsp;  wsp += 128 * 128;
  unsigned short* qb   = wsp;  wsp += (size_t)N_NODES * DIM;
  unsigned short* Kb   = wsp;  wsp += (size_t)N_NODES * DIM;
  unsigned short* Vb   = wsp;  wsp += (size_t)N_NODES * DIM;
  unsigned short* WeKb = wsp;  wsp += (size_t)N_EDGES * DIM;
  unsigned short* ctxb = wsp;  wsp += (size_t)N_NODES * DIM;

  wprep_kernel<<<dim3(288), dim3(256), 0, stream>>>(Wq, Wk, Wv, Wlin, Wedge, Wo, CW, CWE, Wob);
  g12_kernel<<<dim3(1024), dim3(256), 0, stream>>>(x, CW, bq, bv, qb, Kb, Vb, ea, CWE, bk, WeKb);
  attn_kernel<<<dim3(32768), dim3(64), 0, stream>>>(qb, Kb, Vb, WeKb, nedges, enodes, ctxb);
  g4_kernel<<<dim3(512, 2), dim3(256), 0, stream>>>(ctxb, Wob, bo, out);
}

// Round 6
// 201.499 us; speedup vs baseline: 1.1425x; 1.0082x over previous
//
#include <hip/hip_runtime.h>

#define N_NODES 32768
#define N_EDGES 16384
#define DEG 4
#define KPE 8
#define DIM 128
#define EDIM 64

typedef float f32x4 __attribute__((ext_vector_type(4)));
typedef __bf16 bf16x8 __attribute__((ext_vector_type(8)));
typedef __bf16 bf16x2 __attribute__((ext_vector_type(2)));
typedef unsigned short u16x8 __attribute__((ext_vector_type(8)));
typedef unsigned int u32;
typedef unsigned int u32x4 __attribute__((ext_vector_type(4)));

static __device__ __forceinline__ unsigned short f2bf(float f) {
  union { float f; unsigned int u; } v; v.f = f;
  unsigned int r = (v.u + 0x7FFFu + ((v.u >> 16) & 1u)) >> 16;
  return (unsigned short)r;
}
static __device__ __forceinline__ float bflo(unsigned int v) {
  union { unsigned int u; float f; } x; x.u = v << 16; return x.f;
}
static __device__ __forceinline__ float bfhi(unsigned int v) {
  union { unsigned int u; float f; } x; x.u = v & 0xffff0000u; return x.f;
}

#if __has_builtin(__builtin_amdgcn_fdot2_f32_bf16)
static __device__ __forceinline__ float dot2bf(unsigned int a, unsigned int b, float c) {
  return __builtin_amdgcn_fdot2_f32_bf16(
      __builtin_bit_cast(bf16x2, a), __builtin_bit_cast(bf16x2, b), c, false);
}
#else
static __device__ __forceinline__ float dot2bf(unsigned int a, unsigned int b, float c) {
  c = fmaf(bflo(a), bflo(b), c);
  return fmaf(bfhi(a), bfhi(b), c);
}
#endif

// ---------------- weight combine: CW=[0.25*Wq@Wlin; Wk@Wlin; Wv@Wlin] (384x128),
// CWE = Wk@Wedge (128x64), Wob = bf16(Wo) ----------------
__global__ __launch_bounds__(256) void wprep_kernel(
    const float* __restrict__ Wq, const float* __restrict__ Wk,
    const float* __restrict__ Wv, const float* __restrict__ Wlin,
    const float* __restrict__ Wedge, const float* __restrict__ Wo,
    unsigned short* __restrict__ CW, unsigned short* __restrict__ CWE,
    unsigned short* __restrict__ Wob)
{
  int id = blockIdx.x * 256 + threadIdx.x;
  if (id < 384 * 128) {
    int j = id >> 7, i = id & 127;
    const float* wrow; float scale = 1.0f;
    if (j < 128)      { wrow = Wq + j * 128; scale = 0.25f; }
    else if (j < 256) { wrow = Wk + (j - 128) * 128; }
    else              { wrow = Wv + (j - 256) * 128; }
    float s = 0.f;
    #pragma unroll 8
    for (int m = 0; m < 128; ++m) s += wrow[m] * Wlin[m * 128 + i];
    CW[id] = f2bf(s * scale);
  } else if (id < 384 * 128 + 128 * 64) {
    int id2 = id - 384 * 128; int j = id2 >> 6, t = id2 & 63;
    float s = 0.f;
    #pragma unroll 8
    for (int m = 0; m < 128; ++m) s += Wk[j * 128 + m] * Wedge[m * 64 + t];
    CWE[id2] = f2bf(s);
  } else if (id < 384 * 128 + 128 * 64 + 128 * 128) {
    int id3 = id - (384 * 128 + 128 * 64);
    Wob[id3] = f2bf(Wo[id3]);
  }
}

// ---------------- G12: fused g1 + g2 (independent work, one launch) -----------
__global__ __launch_bounds__(256) void g12_kernel(
    const float* __restrict__ x, const unsigned short* __restrict__ CW,
    const float* __restrict__ bq, const float* __restrict__ bv,
    unsigned short* __restrict__ qb, unsigned short* __restrict__ Kb,
    unsigned short* __restrict__ Vb,
    const float* __restrict__ ea, const unsigned short* __restrict__ CWE,
    const float* __restrict__ bk, unsigned short* __restrict__ WeKb)
{
  const int wave = threadIdx.x >> 6, lane = threadIdx.x & 63;
  const int r16 = lane & 15, quad = lane >> 4;

  if (blockIdx.x < 512) {
    const int m0 = blockIdx.x * 64 + wave * 16;
    u16x8 av[4];
    const float* arow = x + (size_t)(m0 + r16) * DIM + quad * 8;
    #pragma unroll
    for (int kk = 0; kk < 4; ++kk) {
      float4 a0 = *(const float4*)(arow + kk * 32);
      float4 a1 = *(const float4*)(arow + kk * 32 + 4);
      u16x8 au;
      au[0] = f2bf(a0.x); au[1] = f2bf(a0.y); au[2] = f2bf(a0.z); au[3] = f2bf(a0.w);
      au[4] = f2bf(a1.x); au[5] = f2bf(a1.y); au[6] = f2bf(a1.z); au[7] = f2bf(a1.w);
      av[kk] = au;
    }
    #pragma unroll
    for (int g = 0; g < 6; ++g) {
      f32x4 acc[4];
      const f32x4 z = {0.f, 0.f, 0.f, 0.f};
      acc[0] = z; acc[1] = z; acc[2] = z; acc[3] = z;
      #pragma unroll
      for (int kk = 0; kk < 4; ++kk) {
        #pragma unroll
        for (int s = 0; s < 4; ++s) {
          u16x8 bu = *(const u16x8*)(CW + (size_t)(g * 64 + s * 16 + r16) * DIM + kk * 32 + quad * 8);
          acc[s] = __builtin_amdgcn_mfma_f32_16x16x32_bf16(
              __builtin_bit_cast(bf16x8, av[kk]), __builtin_bit_cast(bf16x8, bu), acc[s], 0, 0, 0);
        }
      }
      const int arr = g >> 1;               // 0:q 1:K 2:V
      const int colbase = (g & 1) * 64;
      unsigned short* dst = arr == 0 ? qb : (arr == 1 ? Kb : Vb);
      #pragma unroll
      for (int s = 0; s < 4; ++s) {
        int j = colbase + s * 16 + r16;
        float bias = arr == 0 ? 0.25f * bq[j] : (arr == 2 ? bv[j] : 0.f);
        #pragma unroll
        for (int r = 0; r < 4; ++r) {
          int m = m0 + quad * 4 + r;
          dst[(size_t)m * DIM + j] = f2bf(acc[s][r] + bias);
        }
      }
    }
  } else {
    const int idx = blockIdx.x - 512;
    const int m0 = (idx >> 1) * 64 + wave * 16;
    const int n0 = (idx & 1) * 64;
    f32x4 acc[4];
    const f32x4 z = {0.f, 0.f, 0.f, 0.f};
    acc[0] = z; acc[1] = z; acc[2] = z; acc[3] = z;
    const float* arow = ea + (size_t)(m0 + r16) * EDIM + quad * 8;
    #pragma unroll
    for (int kk = 0; kk < 2; ++kk) {
      float4 a0 = *(const float4*)(arow + kk * 32);
      float4 a1 = *(const float4*)(arow + kk * 32 + 4);
      u16x8 au;
      au[0] = f2bf(a0.x); au[1] = f2bf(a0.y); au[2] = f2bf(a0.z); au[3] = f2bf(a0.w);
      au[4] = f2bf(a1.x); au[5] = f2bf(a1.y); au[6] = f2bf(a1.z); au[7] = f2bf(a1.w);
      bf16x8 av = __builtin_bit_cast(bf16x8, au);
      #pragma unroll
      for (int s = 0; s < 4; ++s) {
        u16x8 bu = *(const u16x8*)(CWE + (size_t)(n0 + s * 16 + r16) * EDIM + kk * 32 + quad * 8);
        acc[s] = __builtin_amdgcn_mfma_f32_16x16x32_bf16(
            av, __builtin_bit_cast(bf16x8, bu), acc[s], 0, 0, 0);
      }
    }
    #pragma unroll
    for (int s = 0; s < 4; ++s) {
      int j = n0 + s * 16 + r16;
      float bias = bk[j];
      #pragma unroll
      for (int r = 0; r < 4; ++r) {
        int m = m0 + quad * 4 + r;
        WeKb[(size_t)m * DIM + j] = f2bf(acc[s][r] + bias);
      }
    }
  }
}

// ---------------- G3: per-node attention (1 block = 1 wave = 1 node) ----------
// r5 + enforced software pipeline:
//   issue K/E DMA (36) -> q nt-loads (8) -> [asm fence: orders q before V]
//   -> V loads (32) -> [asm s_waitcnt vmcnt(32): retires exactly DMA+q]
//   -> scores/softmax with all 32 V loads STILL IN FLIGHT -> ctx.
// The two memory-clobber asms make the V-load sinking (r5: VGPR=52, V latency
// exposed at ctx) impossible: loads cannot cross an asm in either direction.
// q/ctx use nontemporal ops so the 16 MB of stream traffic stops thrashing the
// 4 MB/XCD L2 that the K/V/WeK gather tables need.
__global__ __launch_bounds__(64, 4) void attn_kernel(
    const unsigned short* __restrict__ qb, const unsigned short* __restrict__ Kb,
    const unsigned short* __restrict__ Vb, const unsigned short* __restrict__ WeKb,
    const int* __restrict__ nedges, const int* __restrict__ enodes,
    unsigned short* __restrict__ ctxb)
{
  __shared__ __align__(16) unsigned char ldsK[32 * 272];  // K rows, stride 272
  __shared__ __align__(16) unsigned char ldsE[4 * 272];   // WeK rows
  __shared__ __align__(16) float ldsP[8][36];             // P, padded stride
  const int lane = threadIdx.x;
  const int n = blockIdx.x;
  const int l = lane & 31, half = lane >> 5;
  const int h = lane >> 3;                                 // ctx head
  const int c0 = lane * 2;                                 // ctx dim pair

  // --- indices (wave-uniform rows) ---
  int4 e4 = *(const int4*)(nedges + (size_t)n * DEG);
  int4 m0 = *(const int4*)(enodes + (size_t)e4.x * KPE);
  int4 m1 = *(const int4*)(enodes + (size_t)e4.x * KPE + 4);
  int4 m2 = *(const int4*)(enodes + (size_t)e4.y * KPE);
  int4 m3 = *(const int4*)(enodes + (size_t)e4.y * KPE + 4);
  int4 m4 = *(const int4*)(enodes + (size_t)e4.z * KPE);
  int4 m5 = *(const int4*)(enodes + (size_t)e4.z * KPE + 4);
  int4 m6 = *(const int4*)(enodes + (size_t)e4.w * KPE);
  int4 m7 = *(const int4*)(enodes + (size_t)e4.w * KPE + 4);

  // --- K + WeK rows -> LDS DMA (oldest VMEM ops: 36 instrs) ---
#define STAGE(ldsdst, table, row) do {                                          \
    const u32* gp_ = (const u32*)((table) + (size_t)(row) * DIM) + lane;        \
    __builtin_amdgcn_global_load_lds(                                           \
        (const __attribute__((address_space(1))) u32*)gp_,                      \
        (__attribute__((address_space(3))) u32*)(ldsdst), 4, 0, 0);             \
  } while (0)
  STAGE(ldsK + 0  * 272, Kb, m0.x); STAGE(ldsK + 1  * 272, Kb, m0.y);
  STAGE(ldsK + 2  * 272, Kb, m0.z); STAGE(ldsK + 3  * 272, Kb, m0.w);
  STAGE(ldsK + 4  * 272, Kb, m1.x); STAGE(ldsK + 5  * 272, Kb, m1.y);
  STAGE(ldsK + 6  * 272, Kb, m1.z); STAGE(ldsK + 7  * 272, Kb, m1.w);
  STAGE(ldsK + 8  * 272, Kb, m2.x); STAGE(ldsK + 9  * 272, Kb, m2.y);
  STAGE(ldsK + 10 * 272, Kb, m2.z); STAGE(ldsK + 11 * 272, Kb, m2.w);
  STAGE(ldsK + 12 * 272, Kb, m3.x); STAGE(ldsK + 13 * 272, Kb, m3.y);
  STAGE(ldsK + 14 * 272, Kb, m3.z); STAGE(ldsK + 15 * 272, Kb, m3.w);
  STAGE(ldsK + 16 * 272, Kb, m4.x); STAGE(ldsK + 17 * 272, Kb, m4.y);
  STAGE(ldsK + 18 * 272, Kb, m4.z); STAGE(ldsK + 19 * 272, Kb, m4.w);
  STAGE(ldsK + 20 * 272, Kb, m5.x); STAGE(ldsK + 21 * 272, Kb, m5.y);
  STAGE(ldsK + 22 * 272, Kb, m5.z); STAGE(ldsK + 23 * 272, Kb, m5.w);
  STAGE(ldsK + 24 * 272, Kb, m6.x); STAGE(ldsK + 25 * 272, Kb, m6.y);
  STAGE(ldsK + 26 * 272, Kb, m6.z); STAGE(ldsK + 27 * 272, Kb, m6.w);
  STAGE(ldsK + 28 * 272, Kb, m7.x); STAGE(ldsK + 29 * 272, Kb, m7.y);
  STAGE(ldsK + 30 * 272, Kb, m7.z); STAGE(ldsK + 31 * 272, Kb, m7.w);
  STAGE(ldsE + 0 * 272, WeKb, e4.x); STAGE(ldsE + 1 * 272, WeKb, e4.y);
  STAGE(ldsE + 2 * 272, WeKb, e4.z); STAGE(ldsE + 3 * 272, WeKb, e4.w);
#undef STAGE

  // --- q (wave-uniform row): nontemporal, next-oldest 8 VMEM ops ---
  const u32x4* qp = (const u32x4*)(qb + (size_t)n * DIM + half * 64);
  u32x4 qv[8];
  #pragma unroll
  for (int ch = 0; ch < 8; ++ch) qv[ch] = __builtin_nontemporal_load(qp + ch);

  // Fence 1: pins DMA+q issue before V issue (makes vmcnt(32) math exact).
  asm volatile("" ::: "memory");

  // --- V rows (coalesced 256 B wave reads) -> regs: youngest 32 VMEM ops ---
  u32 vv[32];
#define VLOAD(t, row) vv[t] = *(const u32*)(Vb + (size_t)(row) * DIM + c0)
  VLOAD(0,  m0.x); VLOAD(1,  m0.y); VLOAD(2,  m0.z); VLOAD(3,  m0.w);
  VLOAD(4,  m1.x); VLOAD(5,  m1.y); VLOAD(6,  m1.z); VLOAD(7,  m1.w);
  VLOAD(8,  m2.x); VLOAD(9,  m2.y); VLOAD(10, m2.z); VLOAD(11, m2.w);
  VLOAD(12, m3.x); VLOAD(13, m3.y); VLOAD(14, m3.z); VLOAD(15, m3.w);
  VLOAD(16, m4.x); VLOAD(17, m4.y); VLOAD(18, m4.z); VLOAD(19, m4.w);
  VLOAD(20, m5.x); VLOAD(21, m5.y); VLOAD(22, m5.z); VLOAD(23, m5.w);
  VLOAD(24, m6.x); VLOAD(25, m6.y); VLOAD(26, m6.z); VLOAD(27, m6.w);
  VLOAD(28, m7.x); VLOAD(29, m7.y); VLOAD(30, m7.z); VLOAD(31, m7.w);
#undef VLOAD

  // Fence 2: retire exactly the oldest 44 ops (all DMAs + q); the 32 V loads
  // remain in flight under the score/softmax compute below.
  asm volatile("s_waitcnt vmcnt(32)" ::: "memory");

  // --- scores: s[hi] = q . (K[l] + WeK[e(l)]) over this half's 64 dims ---
  const unsigned char* krow = ldsK + l * 272 + half * 128;
  const unsigned char* erow = ldsE + (l >> 3) * 272 + half * 128;
  float s[4] = {0.f, 0.f, 0.f, 0.f};
  #pragma unroll
  for (int ch = 0; ch < 8; ++ch) {
    uint4 kc = *(const uint4*)(krow + ch * 16);
    uint4 ec = *(const uint4*)(erow + ch * 16);
    const int hi = ch >> 1;
    float t = s[hi];
    t = dot2bf(qv[ch].x, kc.x, t); t = dot2bf(qv[ch].x, ec.x, t);
    t = dot2bf(qv[ch].y, kc.y, t); t = dot2bf(qv[ch].y, ec.y, t);
    t = dot2bf(qv[ch].z, kc.z, t); t = dot2bf(qv[ch].z, ec.z, t);
    t = dot2bf(qv[ch].w, kc.w, t); t = dot2bf(qv[ch].w, ec.w, t);
    s[hi] = t;
  }

  // --- softmax over the 32 keys (within each 32-lane half-group) ---
  #pragma unroll
  for (int hi = 0; hi < 4; ++hi) {
    float vmax = s[hi];
    #pragma unroll
    for (int off = 16; off >= 1; off >>= 1)
      vmax = fmaxf(vmax, __shfl_xor(vmax, off, 32));
    float ex = __expf(s[hi] - vmax);
    float sum = ex;
    #pragma unroll
    for (int off = 16; off >= 1; off >>= 1)
      sum += __shfl_xor(sum, off, 32);
    ldsP[half * 4 + hi][l] = ex / sum;
  }
  // single-wave block: LDS write->read ordering is just lgkmcnt (compiler).

  // --- ctx: lane = dim pair; V regs (compiler waits precisely), P via LDS ---
  float a0 = 0.f, a1 = 0.f;
  #pragma unroll
  for (int t = 0; t < 8; ++t) {
    float4 p4 = *(const float4*)&ldsP[h][t * 4];
    a0 = fmaf(p4.x, bflo(vv[t * 4 + 0]), a0); a1 = fmaf(p4.x, bfhi(vv[t * 4 + 0]), a1);
    a0 = fmaf(p4.y, bflo(vv[t * 4 + 1]), a0); a1 = fmaf(p4.y, bfhi(vv[t * 4 + 1]), a1);
    a0 = fmaf(p4.z, bflo(vv[t * 4 + 2]), a0); a1 = fmaf(p4.z, bfhi(vv[t * 4 + 2]), a1);
    a0 = fmaf(p4.w, bflo(vv[t * 4 + 3]), a0); a1 = fmaf(p4.w, bfhi(vv[t * 4 + 3]), a1);
  }
  unsigned int pk = (unsigned int)f2bf(a0) | ((unsigned int)f2bf(a1) << 16);
  __builtin_nontemporal_store(pk, (u32*)(ctxb + (size_t)n * DIM + c0));
}

// ---------------- G4: ctx[N,128] @ Wo[128,128]^T + bo, ReLU -> out fp32 -------
__global__ __launch_bounds__(256) void g4_kernel(
    const unsigned short* __restrict__ ctxb, const unsigned short* __restrict__ Wob,
    const float* __restrict__ bo, float* __restrict__ out)
{
  const int wave = threadIdx.x >> 6, lane = threadIdx.x & 63;
  const int r16 = lane & 15, quad = lane >> 4;
  const int m0 = blockIdx.x * 64 + wave * 16;
  const int n0 = blockIdx.y * 64;

  f32x4 acc[4];
  const f32x4 z = {0.f, 0.f, 0.f, 0.f};
  acc[0] = z; acc[1] = z; acc[2] = z; acc[3] = z;

  #pragma unroll
  for (int kk = 0; kk < 4; ++kk) {
    u16x8 au = *(const u16x8*)(ctxb + (size_t)(m0 + r16) * DIM + kk * 32 + quad * 8);
    bf16x8 av = __builtin_bit_cast(bf16x8, au);
    #pragma unroll
    for (int s = 0; s < 4; ++s) {
      u16x8 bu = *(const u16x8*)(Wob + (size_t)(n0 + s * 16 + r16) * DIM + kk * 32 + quad * 8);
      acc[s] = __builtin_amdgcn_mfma_f32_16x16x32_bf16(
          av, __builtin_bit_cast(bf16x8, bu), acc[s], 0, 0, 0);
    }
  }

  #pragma unroll
  for (int s = 0; s < 4; ++s) {
    int j = n0 + s * 16 + r16;
    float bias = bo[j];
    #pragma unroll
    for (int r = 0; r < 4; ++r) {
      int m = m0 + quad * 4 + r;
      float v = acc[s][r] + bias;
      out[(size_t)m * DIM + j] = v > 0.f ? v : 0.f;
    }
  }
}

extern "C" void kernel_launch(void* const* d_in, const int* in_sizes, int n_in,
                              void* d_out, int out_size, void* d_ws, size_t ws_size,
                              hipStream_t stream)
{
  const float* x     = (const float*)d_in[0];
  const float* ea    = (const float*)d_in[1];
  const int* nedges  = (const int*)d_in[2];
  const int* enodes  = (const int*)d_in[3];
  const float* Wlin  = (const float*)d_in[4];
  const float* Wedge = (const float*)d_in[5];
  const float* Wq    = (const float*)d_in[6];
  const float* Wk    = (const float*)d_in[7];
  const float* Wv    = (const float*)d_in[8];
  const float* bq    = (const float*)d_in[9];
  const float* bk    = (const float*)d_in[10];
  const float* bv    = (const float*)d_in[11];
  const float* Wo    = (const float*)d_in[12];
  const float* bo    = (const float*)d_in[13];
  float* out = (float*)d_out;

  unsigned short* wsp = (unsigned short*)d_ws;
  unsigned short* CW   = wsp;  wsp += 384 * 128;
  unsigned short* CWE  = wsp;  wsp += 128 * 64;
  unsigned short* Wob  = wsp;  wsp += 128 * 128;
  unsigned short* qb   = wsp;  wsp += (size_t)N_NODES * DIM;
  unsigned short* Kb   = wsp;  wsp += (size_t)N_NODES * DIM;
  unsigned short* Vb   = wsp;  wsp += (size_t)N_NODES * DIM;
  unsigned short* WeKb = wsp;  wsp += (size_t)N_EDGES * DIM;
  unsigned short* ctxb = wsp;  wsp += (size_t)N_NODES * DIM;

  wprep_kernel<<<dim3(288), dim3(256), 0, stream>>>(Wq, Wk, Wv, Wlin, Wedge, Wo, CW, CWE, Wob);
  g12_kernel<<<dim3(1024), dim3(256), 0, stream>>>(x, CW, bq, bv, qb, Kb, Vb, ea, CWE, bk, WeKb);
  attn_kernel<<<dim3(32768), dim3(64), 0, stream>>>(qb, Kb, Vb, WeKb, nedges, enodes, ctxb);
  g4_kernel<<<dim3(512, 2), dim3(256), 0, stream>>>(ctxb, Wob, bo, out);
}